// Round 9
// baseline (500.485 us; speedup 1.0000x reference)
//
#include <hip/hip_runtime.h>
#include <hip/hip_bf16.h>

typedef __bf16 bf16x8 __attribute__((ext_vector_type(8)));
typedef float  f32x4  __attribute__((ext_vector_type(4)));

#define N_TOT   16384
#define K_TOT   16384
#define HALF_M  ((size_t)128 * 16384)
#define BN      128
#define BK      32
#define KSPLIT  4
#define KQ_LEN  (K_TOT / KSPLIT)      // 4096
#define NQSTEPS (KQ_LEN / BK)         // 128
#define OUT_ELEMS ((size_t)256 * 16384)

__device__ __forceinline__ unsigned short f2bf(float f) {
    __hip_bfloat16 h = __float2bfloat16(f);
    return __builtin_bit_cast(unsigned short, h);
}

// 64-B rows (BK=32 bf16), 16-B granules: XOR granule with (row>>1)&3.
// <=2-way on frag-read and stage-write patterns (R8-verified pattern).
__device__ __forceinline__ int swz64(int row, int g) {
    return row * 64 + (((g ^ ((row >> 1) & 3)) & 3) << 4);
}

// One-time T = concat(x0,x1) fp32 -> bf16 into workspace (linear row-major).
__global__ void cvtT_kernel(const float* __restrict__ x0,
                            const float* __restrict__ x1,
                            unsigned short* __restrict__ wsT) {
    size_t i = (size_t)blockIdx.x * blockDim.x + threadIdx.x;  // 0..524287
    size_t e = i * 8;
    const float* src = (e < HALF_M) ? (x0 + e) : (x1 + (e - HALF_M));
    float4 a = ((const float4*)src)[0];
    float4 b = ((const float4*)src)[1];
    union { unsigned short u[8]; uint4 v; } o;
    o.u[0] = f2bf(a.x); o.u[1] = f2bf(a.y); o.u[2] = f2bf(a.z); o.u[3] = f2bf(a.w);
    o.u[4] = f2bf(b.x); o.u[5] = f2bf(b.y); o.u[6] = f2bf(b.z); o.u[7] = f2bf(b.w);
    ((uint4*)wsT)[i] = o.v;
}

// out += p0 + p1 + p2 (fixed order -> deterministic)
__global__ void combine_kernel(float* __restrict__ out,
                               const float* __restrict__ p0,
                               const float* __restrict__ p1,
                               const float* __restrict__ p2) {
    const size_t n4 = OUT_ELEMS / 4;
    size_t i = (size_t)blockIdx.x * blockDim.x + threadIdx.x;
    for (; i < n4; i += (size_t)gridDim.x * blockDim.x) {
        float4 o = ((const float4*)out)[i];
        float4 a = ((const float4*)p0)[i];
        float4 b = ((const float4*)p1)[i];
        float4 c = ((const float4*)p2)[i];
        o.x += a.x + b.x + c.x;  o.y += a.y + b.y + c.y;
        o.z += a.z + b.z + c.z;  o.w += a.w + b.w + c.w;
        ((float4*)out)[i] = o;
    }
}

// ---- depth-2 static prefetch ----
// A: thread t stages row t's 32 bf16 (64 B) of the step: 4 x uint4.
#define ISSUE_A(S, kt) do {                                                   \
    const uint4* _p = (const uint4*)(arow + (size_t)(kt) * BK);               \
    a##S##_0 = _p[0]; a##S##_1 = _p[1]; a##S##_2 = _p[2]; a##S##_3 = _p[3];   \
} while (0)

#define STAGE_A(S, Ab) do {                                                   \
    *(uint4*)((Ab) + sw0) = a##S##_0;                                         \
    *(uint4*)((Ab) + sw1) = a##S##_1;                                         \
    *(uint4*)((Ab) + sw2) = a##S##_2;                                         \
    *(uint4*)((Ab) + sw3) = a##S##_3;                                         \
} while (0)

// W: lane loads its own MFMA B-fragment source: 8 fp32 (32 B) per nf,
// directly from global. Wave footprint = 16 rows x 128 B contiguous.
#define ISSUE_W(S, kt) do {                                                   \
    const float4* _q0 = (const float4*)(wrow0 + (size_t)(kt) * BK);           \
    w##S##_a0 = _q0[0]; w##S##_a1 = _q0[1];                                   \
    const float4* _q1 = (const float4*)(wrow1 + (size_t)(kt) * BK);           \
    w##S##_b0 = _q1[0]; w##S##_b1 = _q1[1];                                   \
} while (0)

// fp32x8 -> bf16x8 fragment (in-register, no LDS)
#define CVT_W(S) do {                                                         \
    union { unsigned short u[8]; bf16x8 v; } _c0, _c1;                        \
    _c0.u[0]=f2bf(w##S##_a0.x); _c0.u[1]=f2bf(w##S##_a0.y);                   \
    _c0.u[2]=f2bf(w##S##_a0.z); _c0.u[3]=f2bf(w##S##_a0.w);                   \
    _c0.u[4]=f2bf(w##S##_a1.x); _c0.u[5]=f2bf(w##S##_a1.y);                   \
    _c0.u[6]=f2bf(w##S##_a1.z); _c0.u[7]=f2bf(w##S##_a1.w);                   \
    _c1.u[0]=f2bf(w##S##_b0.x); _c1.u[1]=f2bf(w##S##_b0.y);                   \
    _c1.u[2]=f2bf(w##S##_b0.z); _c1.u[3]=f2bf(w##S##_b0.w);                   \
    _c1.u[4]=f2bf(w##S##_b1.x); _c1.u[5]=f2bf(w##S##_b1.y);                   \
    _c1.u[6]=f2bf(w##S##_b1.z); _c1.u[7]=f2bf(w##S##_b1.w);                   \
    _vb0 = _c0.v; _vb1 = _c1.v;                                               \
} while (0)

#define MROW(MF, Ab) do {                                                     \
    bf16x8 _va = *(const bf16x8*)((Ab) + aoff0 + MF * 1024);                  \
    accA##MF = __builtin_amdgcn_mfma_f32_16x16x32_bf16(_va, _vb0, accA##MF, 0,0,0); \
    accB##MF = __builtin_amdgcn_mfma_f32_16x16x32_bf16(_va, _vb1, accB##MF, 0,0,0); \
} while (0)

// wave = 256M x 32N: 16 A-frag reads + 32 MFMA; W frags from registers.
#define COMPUTE(Ab, S) do {                                                   \
    bf16x8 _vb0, _vb1;                                                        \
    CVT_W(S);                                                                 \
    MROW(0, Ab);  MROW(1, Ab);  MROW(2, Ab);  MROW(3, Ab);                    \
    MROW(4, Ab);  MROW(5, Ab);  MROW(6, Ab);  MROW(7, Ab);                    \
    MROW(8, Ab);  MROW(9, Ab);  MROW(10, Ab); MROW(11, Ab);                   \
    MROW(12, Ab); MROW(13, Ab); MROW(14, Ab); MROW(15, Ab);                   \
} while (0)

#define SYNC do {                                                             \
    asm volatile("s_waitcnt lgkmcnt(0)" ::: "memory");                        \
    __builtin_amdgcn_s_barrier();                                             \
    __builtin_amdgcn_sched_barrier(0);                                        \
} while (0)

// GEMM: grid 512 = 128 nstrips x 4 kq (R5 mapping). 256 threads, 4 waves,
// wave owns 256M x 32N. W: global->reg->MFMA (never LDS). A: LDS dbuf,
// 16 KB/step. Barrier only guards the tiny A staging.
__global__ __launch_bounds__(256)
void gemm_ws(const float* __restrict__ W, const float* __restrict__ bias,
             const unsigned short* __restrict__ wsT,
             float* __restrict__ out, float* __restrict__ wsP)
{
    __shared__ uint4 smem_[2 * 16384 / 16];    // 32 KiB: A0,A1 (256 x 64 B)
    char* const sm = (char*)smem_;
    char* const A0 = sm;
    char* const A1 = sm + 16384;

    const int tid  = threadIdx.x;
    const int lane = tid & 63;
    const int wave = tid >> 6;                 // 0..3 -> 32 N-cols each
    const int bid    = blockIdx.x;
    const int kq     = bid >> 7;               // 0..3
    const int nstrip = bid & 127;
    const int n0     = nstrip * BN;
    const int kbase  = kq * KQ_LEN;

    // A staging: thread t owns row t (64 B per step)
    const unsigned short* arow = wsT + (size_t)tid * K_TOT + kbase;
    const int sw0 = swz64(tid, 0);
    const int sw1 = swz64(tid, 1);
    const int sw2 = swz64(tid, 2);
    const int sw3 = swz64(tid, 3);

    // W direct-load rows (one per nf)
    const int nrow0 = n0 + wave * 32 + (lane & 15);
    const float* wrow0 = W + (size_t)nrow0 * K_TOT + kbase + (lane >> 4) * 8;
    const float* wrow1 = wrow0 + (size_t)16 * K_TOT;

    // A-frag read base; XOR term is mf-independent -> mf*1024 immediates
    const int aoff0 = swz64(lane & 15, lane >> 4);

    f32x4 accA0={0,0,0,0}, accA1={0,0,0,0}, accA2={0,0,0,0}, accA3={0,0,0,0};
    f32x4 accA4={0,0,0,0}, accA5={0,0,0,0}, accA6={0,0,0,0}, accA7={0,0,0,0};
    f32x4 accA8={0,0,0,0}, accA9={0,0,0,0}, accA10={0,0,0,0}, accA11={0,0,0,0};
    f32x4 accA12={0,0,0,0}, accA13={0,0,0,0}, accA14={0,0,0,0}, accA15={0,0,0,0};
    f32x4 accB0={0,0,0,0}, accB1={0,0,0,0}, accB2={0,0,0,0}, accB3={0,0,0,0};
    f32x4 accB4={0,0,0,0}, accB5={0,0,0,0}, accB6={0,0,0,0}, accB7={0,0,0,0};
    f32x4 accB8={0,0,0,0}, accB9={0,0,0,0}, accB10={0,0,0,0}, accB11={0,0,0,0};
    f32x4 accB12={0,0,0,0}, accB13={0,0,0,0}, accB14={0,0,0,0}, accB15={0,0,0,0};

    uint4  a0_0, a0_1, a0_2, a0_3, a1_0, a1_1, a1_2, a1_3;
    float4 w0_a0, w0_a1, w0_b0, w0_b1, w1_a0, w1_a1, w1_b0, w1_b1;

    // prologue: fill both pipeline sets
    ISSUE_A(0, 0); ISSUE_W(0, 0);
    ISSUE_A(1, 1); ISSUE_W(1, 1);
    STAGE_A(0, A0);                            // waits vmcnt for A set0 only
    SYNC;

    for (int kt = 0; kt < NQSTEPS; kt += 2) {
        // phase A: compute step kt from A0 + W set0; refill set0 for kt+2
        {
            const bool more = (kt + 2 < NQSTEPS);
            COMPUTE(A0, 0);                    // cvt reads w0 regs first
            if (more) { ISSUE_W(0, kt + 2); ISSUE_A(0, kt + 2); }
            STAGE_A(1, A1);                    // waits vmcnt for A set1
            SYNC;
        }
        // phase B: compute step kt+1 from A1 + W set1; refill set1 for kt+3
        {
            const bool more = (kt + 3 < NQSTEPS);
            COMPUTE(A1, 1);
            if (more) { ISSUE_W(1, kt + 3); ISSUE_A(1, kt + 3); }
            if (kt + 2 < NQSTEPS) STAGE_A(0, A0);
            SYNC;
        }
    }

    // epilogue: kq==0 writes bias+acc to out; kq>0 -> partial buffers.
    float* const dst = (kq == 0) ? out : (wsP + (size_t)(kq - 1) * OUT_ELEMS);
    #pragma unroll
    for (int nf = 0; nf < 2; ++nf) {
        const int col = n0 + wave * 32 + nf * 16 + (lane & 15);
        const float bv = (kq == 0) ? bias[col] : 0.f;
        #pragma unroll
        for (int mf = 0; mf < 16; ++mf) {
            const f32x4 a = (nf == 0)
                ? (mf==0?accA0:mf==1?accA1:mf==2?accA2:mf==3?accA3:
                   mf==4?accA4:mf==5?accA5:mf==6?accA6:mf==7?accA7:
                   mf==8?accA8:mf==9?accA9:mf==10?accA10:mf==11?accA11:
                   mf==12?accA12:mf==13?accA13:mf==14?accA14:accA15)
                : (mf==0?accB0:mf==1?accB1:mf==2?accB2:mf==3?accB3:
                   mf==4?accB4:mf==5?accB5:mf==6?accB6:mf==7?accB7:
                   mf==8?accB8:mf==9?accB9:mf==10?accB10:mf==11?accB11:
                   mf==12?accB12:mf==13?accB13:mf==14?accB14:accB15);
            #pragma unroll
            for (int j = 0; j < 4; ++j) {
                int r = mf * 16 + (lane >> 4) * 4 + j;
                float v = a[j] + bv;
                float* o = (r < 128) ? (dst + (size_t)r * N_TOT + col)
                                     : (dst + HALF_M + (size_t)(r - 128) * N_TOT + col);
                *o = v;
            }
        }
    }
}

extern "C" void kernel_launch(void* const* d_in, const int* in_sizes, int n_in,
                              void* d_out, int out_size, void* d_ws, size_t ws_size,
                              hipStream_t stream) {
    const float* x0 = (const float*)d_in[0];
    const float* x1 = (const float*)d_in[1];
    const float* W  = (const float*)d_in[2];
    const float* b  = (const float*)d_in[3];
    float* out = (float*)d_out;

    const size_t wsT_bytes = (size_t)256 * 16384 * sizeof(unsigned short);  // 8.4 MB

    unsigned short* wsT = (unsigned short*)d_ws;
    float* wsP = (float*)((char*)d_ws + wsT_bytes);

    cvtT_kernel<<<2048, 256, 0, stream>>>(x0, x1, wsT);
    gemm_ws<<<512, 256, 0, stream>>>(W, b, wsT, out, wsP);
    combine_kernel<<<2048, 256, 0, stream>>>(out, wsP, wsP + OUT_ELEMS,
                                             wsP + 2 * OUT_ELEMS);
}

// Round 11
// 310.634 us; speedup vs baseline: 1.6112x; 1.6112x over previous
//
#include <hip/hip_runtime.h>
#include <hip/hip_bf16.h>

typedef __bf16 bf16x8 __attribute__((ext_vector_type(8)));
typedef float  f32x4  __attribute__((ext_vector_type(4)));

#define N_TOT   16384
#define K_TOT   16384
#define HALF_M  ((size_t)128 * 16384)
#define BN      128
#define BK      64
#define KSPLIT  4
#define KQ_LEN  (K_TOT / KSPLIT)      // 4096
#define NQSTEPS (KQ_LEN / BK)         // 64
#define OUT_ELEMS ((size_t)256 * 16384)

__device__ __forceinline__ unsigned short f2bf(float f) {
    __hip_bfloat16 h = __float2bfloat16(f);
    return __builtin_bit_cast(unsigned short, h);
}

// Swizzled byte offset: 128-B rows, 16-B granules, XOR row&7 into granule idx.
__device__ __forceinline__ int swz(int row, int g) {
    return row * 128 + (((g ^ (row & 7)) & 7) << 4);
}

// One-time T = concat(x0,x1) fp32 -> bf16 into workspace (linear row-major).
__global__ void cvtT_kernel(const float* __restrict__ x0,
                            const float* __restrict__ x1,
                            unsigned short* __restrict__ wsT) {
    size_t i = (size_t)blockIdx.x * blockDim.x + threadIdx.x;  // 0..524287
    size_t e = i * 8;
    const float* src = (e < HALF_M) ? (x0 + e) : (x1 + (e - HALF_M));
    float4 a = ((const float4*)src)[0];
    float4 b = ((const float4*)src)[1];
    union { unsigned short u[8]; uint4 v; } o;
    o.u[0] = f2bf(a.x); o.u[1] = f2bf(a.y); o.u[2] = f2bf(a.z); o.u[3] = f2bf(a.w);
    o.u[4] = f2bf(b.x); o.u[5] = f2bf(b.y); o.u[6] = f2bf(b.z); o.u[7] = f2bf(b.w);
    ((uint4*)wsT)[i] = o.v;
}

// out += p0 + p1 + p2 (fixed order -> deterministic)
__global__ void combine_kernel(float* __restrict__ out,
                               const float* __restrict__ p0,
                               const float* __restrict__ p1,
                               const float* __restrict__ p2) {
    const size_t n4 = OUT_ELEMS / 4;   // 1048576 float4
    size_t i = (size_t)blockIdx.x * blockDim.x + threadIdx.x;
    for (; i < n4; i += (size_t)gridDim.x * blockDim.x) {
        float4 o = ((const float4*)out)[i];
        float4 a = ((const float4*)p0)[i];
        float4 b = ((const float4*)p1)[i];
        float4 c = ((const float4*)p2)[i];
        o.x += a.x + b.x + c.x;  o.y += a.y + b.y + c.y;
        o.z += a.z + b.z + c.z;  o.w += a.w + b.w + c.w;
        ((float4*)out)[i] = o;
    }
}

// ---- prefetch/stage macros (depth-2, static register sets) ----
// W loads are NON-TEMPORAL (native f32x4 vectors for the builtin): W is read
// exactly once; nt keeps the 1.07 GB stream from evicting L2-resident wsT.
#define ISSUEW(S, k0) do {                                                    \
    const uint4* _p = (const uint4*)(arow_w + (k0));                          \
    w##S##_0 = _p[0]; w##S##_1 = _p[1];                                       \
    const f32x4* _q = (const f32x4*)(brow + (k0));                            \
    wb##S##_0 = __builtin_nontemporal_load(_q);                               \
    wb##S##_1 = __builtin_nontemporal_load(_q + 1);                           \
} while (0)

#define STAGEW(S, Ab, Bb) do {                                                \
    *(uint4*)((Ab) + aw0) = w##S##_0;                                         \
    *(uint4*)((Ab) + aw1) = w##S##_1;                                         \
    union { unsigned short u[8]; uint4 v; } _tb;                              \
    _tb.u[0]=f2bf(wb##S##_0[0]); _tb.u[1]=f2bf(wb##S##_0[1]);                 \
    _tb.u[2]=f2bf(wb##S##_0[2]); _tb.u[3]=f2bf(wb##S##_0[3]);                 \
    _tb.u[4]=f2bf(wb##S##_1[0]); _tb.u[5]=f2bf(wb##S##_1[1]);                 \
    _tb.u[6]=f2bf(wb##S##_1[2]); _tb.u[7]=f2bf(wb##S##_1[3]);                 \
    *(uint4*)((Bb) + bw) = _tb.v;                                             \
} while (0)

// 16 waves as 4M x 4N over 256M x 128N: wave owns 64M x 32N.
// 8 A-reads + 4 B-reads + 16 MFMA per step.
#define COMPUTE(Ab, Bb) do {                                                  \
    bf16x8 _b00 = *(const bf16x8*)((Bb) + boff00);                            \
    bf16x8 _b01 = *(const bf16x8*)((Bb) + boff01);                            \
    bf16x8 _b10 = *(const bf16x8*)((Bb) + boff10);                            \
    bf16x8 _b11 = *(const bf16x8*)((Bb) + boff11);                            \
    bf16x8 _a;                                                                \
    _a = *(const bf16x8*)((Ab) + aoff00);                                     \
    acc00 = __builtin_amdgcn_mfma_f32_16x16x32_bf16(_a, _b00, acc00, 0, 0, 0);\
    acc01 = __builtin_amdgcn_mfma_f32_16x16x32_bf16(_a, _b10, acc01, 0, 0, 0);\
    _a = *(const bf16x8*)((Ab) + aoff01);                                     \
    acc00 = __builtin_amdgcn_mfma_f32_16x16x32_bf16(_a, _b01, acc00, 0, 0, 0);\
    acc01 = __builtin_amdgcn_mfma_f32_16x16x32_bf16(_a, _b11, acc01, 0, 0, 0);\
    _a = *(const bf16x8*)((Ab) + aoff10);                                     \
    acc10 = __builtin_amdgcn_mfma_f32_16x16x32_bf16(_a, _b00, acc10, 0, 0, 0);\
    acc11 = __builtin_amdgcn_mfma_f32_16x16x32_bf16(_a, _b10, acc11, 0, 0, 0);\
    _a = *(const bf16x8*)((Ab) + aoff11);                                     \
    acc10 = __builtin_amdgcn_mfma_f32_16x16x32_bf16(_a, _b01, acc10, 0, 0, 0);\
    acc11 = __builtin_amdgcn_mfma_f32_16x16x32_bf16(_a, _b11, acc11, 0, 0, 0);\
    _a = *(const bf16x8*)((Ab) + aoff20);                                     \
    acc20 = __builtin_amdgcn_mfma_f32_16x16x32_bf16(_a, _b00, acc20, 0, 0, 0);\
    acc21 = __builtin_amdgcn_mfma_f32_16x16x32_bf16(_a, _b10, acc21, 0, 0, 0);\
    _a = *(const bf16x8*)((Ab) + aoff21);                                     \
    acc20 = __builtin_amdgcn_mfma_f32_16x16x32_bf16(_a, _b01, acc20, 0, 0, 0);\
    acc21 = __builtin_amdgcn_mfma_f32_16x16x32_bf16(_a, _b11, acc21, 0, 0, 0);\
    _a = *(const bf16x8*)((Ab) + aoff30);                                     \
    acc30 = __builtin_amdgcn_mfma_f32_16x16x32_bf16(_a, _b00, acc30, 0, 0, 0);\
    acc31 = __builtin_amdgcn_mfma_f32_16x16x32_bf16(_a, _b10, acc31, 0, 0, 0);\
    _a = *(const bf16x8*)((Ab) + aoff31);                                     \
    acc30 = __builtin_amdgcn_mfma_f32_16x16x32_bf16(_a, _b01, acc30, 0, 0, 0);\
    acc31 = __builtin_amdgcn_mfma_f32_16x16x32_bf16(_a, _b11, acc31, 0, 0, 0);\
} while (0)

#define SYNC do {                                                             \
    asm volatile("s_waitcnt lgkmcnt(0)" ::: "memory");                        \
    __builtin_amdgcn_s_barrier();                                             \
    __builtin_amdgcn_sched_barrier(0);                                        \
} while (0)

// GEMM: grid 512 = 128 n-strips x 4 k-quarters (kq=bid>>7, R5 mapping —
// best measured). BN=128, BK=64, 16 waves.
__global__ __launch_bounds__(1024, 4)
void gemm_ws(const float* __restrict__ W, const float* __restrict__ bias,
             const unsigned short* __restrict__ wsT,
             float* __restrict__ out, float* __restrict__ wsP)
{
    __shared__ uint4 smem_[(2 * 32768 + 2 * 16384) / 16];   // 96 KiB
    char* const sm = (char*)smem_;
    char* const A0 = sm;                       // A: 256 rows x 128 B
    char* const A1 = sm + 32768;
    char* const B0 = sm + 65536;               // B: 128 rows x 128 B
    char* const B1 = sm + 65536 + 16384;

    const int tid  = threadIdx.x;
    const int lane = tid & 63;
    const int wave = tid >> 6;
    const int wm = wave >> 2;                  // 0..3 (64 M rows)
    const int wn = wave & 3;                   // 0..3 (32 N cols)
    const int bid    = blockIdx.x;
    const int kq     = bid >> 7;               // 0..3
    const int nstrip = bid & 127;
    const int n0     = nstrip * BN;
    const int kbase  = kq * KQ_LEN;

    // staging geometry
    const int ra  = tid >> 2;                  // A row 0..255
    const int pa  = tid & 3;                   // 32-B chunk of 128-B row
    const int rbs = tid >> 3;                  // B row 0..127

    const unsigned short* arow_w = wsT + (size_t)ra * K_TOT + kbase + pa * 16;
    const float* brow = W + (size_t)(n0 + rbs) * K_TOT + kbase + (tid & 7) * 8;

    const int aw0 = swz(ra, 2 * pa);
    const int aw1 = swz(ra, 2 * pa + 1);
    const int bw  = swz(rbs, tid & 7);

    // compute-side LDS read offsets
    const int aoff00 = swz(wm * 64 +  0 + (lane & 15), 0 + (lane >> 4));
    const int aoff01 = swz(wm * 64 +  0 + (lane & 15), 4 + (lane >> 4));
    const int aoff10 = swz(wm * 64 + 16 + (lane & 15), 0 + (lane >> 4));
    const int aoff11 = swz(wm * 64 + 16 + (lane & 15), 4 + (lane >> 4));
    const int aoff20 = swz(wm * 64 + 32 + (lane & 15), 0 + (lane >> 4));
    const int aoff21 = swz(wm * 64 + 32 + (lane & 15), 4 + (lane >> 4));
    const int aoff30 = swz(wm * 64 + 48 + (lane & 15), 0 + (lane >> 4));
    const int aoff31 = swz(wm * 64 + 48 + (lane & 15), 4 + (lane >> 4));
    const int boff00 = swz(wn * 32 +  0 + (lane & 15), 0 + (lane >> 4));
    const int boff01 = swz(wn * 32 +  0 + (lane & 15), 4 + (lane >> 4));
    const int boff10 = swz(wn * 32 + 16 + (lane & 15), 0 + (lane >> 4));
    const int boff11 = swz(wn * 32 + 16 + (lane & 15), 4 + (lane >> 4));

    f32x4 acc00 = {0.f,0.f,0.f,0.f}, acc01 = {0.f,0.f,0.f,0.f};
    f32x4 acc10 = {0.f,0.f,0.f,0.f}, acc11 = {0.f,0.f,0.f,0.f};
    f32x4 acc20 = {0.f,0.f,0.f,0.f}, acc21 = {0.f,0.f,0.f,0.f};
    f32x4 acc30 = {0.f,0.f,0.f,0.f}, acc31 = {0.f,0.f,0.f,0.f};

    uint4 w0_0, w0_1, w1_0, w1_1;
    f32x4 wb0_0, wb0_1, wb1_0, wb1_1;

    ISSUEW(0, 0);
    ISSUEW(1, BK);
    STAGEW(0, A0, B0);
    SYNC;

    for (int kt = 0; kt < NQSTEPS; kt += 2) {
        if (kt + 2 < NQSTEPS) ISSUEW(0, (kt + 2) * BK);
        COMPUTE(A0, B0);
        STAGEW(1, A1, B1);
        SYNC;
        if (kt + 3 < NQSTEPS) ISSUEW(1, (kt + 3) * BK);
        COMPUTE(A1, B1);
        if (kt + 2 < NQSTEPS) STAGEW(0, A0, B0);
        SYNC;
    }

    // epilogue: kq==0 writes bias+acc to out; kq>0 writes acc to partial buf.
    float* const dst = (kq == 0) ? out : (wsP + (size_t)(kq - 1) * OUT_ELEMS);
    #pragma unroll
    for (int nf = 0; nf < 2; ++nf) {
        const int col = n0 + wn * 32 + nf * 16 + (lane & 15);
        const float bv = (kq == 0) ? bias[col] : 0.f;
        #pragma unroll
        for (int mf = 0; mf < 4; ++mf) {
            const f32x4 a =
                (nf == 0) ? (mf == 0 ? acc00 : mf == 1 ? acc10 : mf == 2 ? acc20 : acc30)
                          : (mf == 0 ? acc01 : mf == 1 ? acc11 : mf == 2 ? acc21 : acc31);
            #pragma unroll
            for (int j = 0; j < 4; ++j) {
                int r = wm * 64 + mf * 16 + (lane >> 4) * 4 + j;
                float v = a[j] + bv;
                float* o = (r < 128) ? (dst + (size_t)r * N_TOT + col)
                                     : (dst + HALF_M + (size_t)(r - 128) * N_TOT + col);
                *o = v;
            }
        }
    }
}

extern "C" void kernel_launch(void* const* d_in, const int* in_sizes, int n_in,
                              void* d_out, int out_size, void* d_ws, size_t ws_size,
                              hipStream_t stream) {
    const float* x0 = (const float*)d_in[0];
    const float* x1 = (const float*)d_in[1];
    const float* W  = (const float*)d_in[2];
    const float* b  = (const float*)d_in[3];
    float* out = (float*)d_out;

    const size_t wsT_bytes = (size_t)256 * 16384 * sizeof(unsigned short);  // 8.4 MB

    unsigned short* wsT = (unsigned short*)d_ws;
    float* wsP = (float*)((char*)d_ws + wsT_bytes);

    cvtT_kernel<<<2048, 256, 0, stream>>>(x0, x1, wsT);
    gemm_ws<<<512, 1024, 0, stream>>>(W, b, wsT, out, wsP);
    combine_kernel<<<2048, 256, 0, stream>>>(out, wsP, wsP + OUT_ELEMS,
                                             wsP + 2 * OUT_ELEMS);
}